// Round 1
// baseline (1109.193 us; speedup 1.0000x reference)
//
#include <hip/hip_runtime.h>

#define N_NODES 50000
#define N_EDGES 500000
#define DIM 128
#define KC 1024
#define CAP 64
#define EPSV 1e-8f

// ---------------- Stage 1a: bucket edges by dst (int atomics only) ----------------
__global__ void fill_buckets_k(const int* __restrict__ ei, int* __restrict__ bucket,
                               int* __restrict__ cursor) {
    int e = blockIdx.x * blockDim.x + threadIdx.x;
    if (e >= N_EDGES) return;
    int src = ei[e];
    int dst = ei[N_EDGES + e];
    int pos = atomicAdd(cursor + dst, 1);
    if (pos < CAP) bucket[dst * CAP + pos] = src;
}

// ---------------- Stage 1b+2: deterministic mean-aggregate + L2 normalize ----------
// one wave (64 lanes) per node; bitonic-sort the bucket so the float sum order is
// bit-deterministic across replays (graph replay re-validation!)
__global__ void agg_norm_k(const float* __restrict__ x, const int* __restrict__ bucket,
                           const int* __restrict__ cursor, float* __restrict__ h,
                           float* __restrict__ hn) {
    int lane = threadIdx.x & 63;
    int wv = threadIdx.x >> 6;
    int n = blockIdx.x * 4 + wv;  // grid 12500 * 4 waves = 50000 exactly

    int cnt = cursor[n];
    if (cnt > CAP) cnt = CAP;
    int v = (lane < cnt) ? bucket[n * CAP + lane] : 0x7fffffff;

    // bitonic sort ascending across 64 lanes (21 compare-exchange steps)
#pragma unroll
    for (int k = 2; k <= 64; k <<= 1) {
#pragma unroll
        for (int j = k >> 1; j >= 1; j >>= 1) {
            int other = __shfl_xor(v, j);
            bool lower = ((lane & j) == 0);
            bool asc = ((lane & k) == 0);
            int mn = min(v, other), mx = max(v, other);
            v = (lower == asc) ? mn : mx;
        }
    }

    const float2* x2 = (const float2*)x;
    float ax = 0.f, ay = 0.f;
    for (int j = 0; j < cnt; ++j) {
        int s = __shfl(v, j);                    // uniform, sorted -> deterministic
        float2 t = x2[(size_t)s * 64 + lane];    // 512B coalesced row read
        ax += t.x; ay += t.y;
    }
    float degf = (float)(cnt > 0 ? cnt : 1);
    float hx = ax / degf, hy = ay / degf;

    float ss = hx * hx + hy * hy;
#pragma unroll
    for (int o = 1; o < 64; o <<= 1) ss += __shfl_xor(ss, o);
    float denom = sqrtf(ss) + EPSV;
    float hnx = hx / denom, hny = hy / denom;

    ((float2*)h)[(size_t)n * 64 + lane] = make_float2(hx, hy);
    ((float2*)hn)[(size_t)n * 64 + lane] = make_float2(hnx, hny);
}

// ---------------- Stage 3: sim = hn @ hn[:1024].T, argmax ----------------
// 1 thread = 1 node; full row in 128 VGPRs; centroid reads are wave-uniform ->
// scalar loads + v_fma with SGPR operand. 4 acc chains for FMA-latency ILP.
__global__ __launch_bounds__(64) void sim_argmax_k(const float* __restrict__ hn,
                                                   int* __restrict__ assign) {
    int n = blockIdx.x * 64 + threadIdx.x;
    if (n >= N_NODES) return;

    float4 r[32];
    const float4* row4 = (const float4*)(hn + (size_t)n * DIM);
#pragma unroll
    for (int i = 0; i < 32; ++i) r[i] = row4[i];

    float best = -1e30f;
    int bi = 0;
    for (int c = 0; c < KC; ++c) {
        const float4* c4 = (const float4*)(hn + (size_t)c * DIM);  // uniform
        float a0 = 0.f, a1 = 0.f, a2 = 0.f, a3 = 0.f;
#pragma unroll
        for (int kk = 0; kk < 32; ++kk) {
            float4 cv = c4[kk];
            a0 = fmaf(r[kk].x, cv.x, a0);
            a1 = fmaf(r[kk].y, cv.y, a1);
            a2 = fmaf(r[kk].z, cv.z, a2);
            a3 = fmaf(r[kk].w, cv.w, a3);
        }
        float s = (a0 + a1) + (a2 + a3);
        if (s > best) { best = s; bi = c; }   // strict > keeps FIRST max (np argmax)
    }
    assign[n] = bi;
}

// ---------------- Stage 4: cluster sums (float atomics OK: smooth path) ----------
__global__ void cluster_acc_k(const float* __restrict__ h, const int* __restrict__ assign,
                              float* __restrict__ xc, int* __restrict__ counts) {
    int i = blockIdx.x * blockDim.x + threadIdx.x;  // 50000*32 exactly
    int n = i >> 5, q = i & 31;
    int a = assign[n];
    float4 v = ((const float4*)h)[(size_t)n * 32 + q];
    float* d = xc + a * DIM + q * 4;
    atomicAdd(d + 0, v.x);
    atomicAdd(d + 1, v.y);
    atomicAdd(d + 2, v.z);
    atomicAdd(d + 3, v.w);
    if (q == 0) atomicAdd(counts + a, 1);
}

// ---------------- Stage 5: y = (xc/counts) @ W1.T + b1 ----------------
__global__ void y_gemm_k(const float* __restrict__ xc, const int* __restrict__ counts,
                         const float* __restrict__ W1, const float* __restrict__ b1,
                         float* __restrict__ y) {
    __shared__ float xr[DIM];
    int c = blockIdx.x, t = threadIdx.x;  // 1024 blocks x 128 threads
    int cnt = counts[c];
    float cntf = (float)(cnt > 0 ? cnt : 1);
    xr[t] = xc[c * DIM + t] / cntf;
    __syncthreads();

    const float4* w4 = (const float4*)(W1 + t * DIM);
    float a0 = 0.f, a1 = 0.f, a2 = 0.f, a3 = 0.f;
#pragma unroll
    for (int kk = 0; kk < 32; ++kk) {
        float4 w = w4[kk];
        a0 = fmaf(xr[4 * kk + 0], w.x, a0);
        a1 = fmaf(xr[4 * kk + 1], w.y, a1);
        a2 = fmaf(xr[4 * kk + 2], w.z, a2);
        a3 = fmaf(xr[4 * kk + 3], w.w, a3);
    }
    y[c * DIM + t] = (a0 + a1) + (a2 + a3) + b1[t];
}

// ---------------- Stage 6: out = y[assign] ----------------
__global__ void scatter_out_k(const float* __restrict__ y, const int* __restrict__ assign,
                              float* __restrict__ out) {
    int i = blockIdx.x * blockDim.x + threadIdx.x;  // 50000*32 exactly
    int n = i >> 5, q = i & 31;
    int a = assign[n];
    ((float4*)out)[(size_t)n * 32 + q] = ((const float4*)y)[a * 32 + q];
}

extern "C" void kernel_launch(void* const* d_in, const int* in_sizes, int n_in,
                              void* d_out, int out_size, void* d_ws, size_t ws_size,
                              hipStream_t stream) {
    const float* x  = (const float*)d_in[0];
    const int*   ei = (const int*)d_in[1];
    const float* W1 = (const float*)d_in[2];
    const float* b1 = (const float*)d_in[3];
    float* out = (float*)d_out;

    char* ws = (char*)d_ws;
    // layout (bytes):
    //   h      @ 0          : 50000*128*4 = 25,600,000
    //   bucket @ 25,600,000 : 50000*64*4  = 12,800,000
    //   cursor @ 38,400,000 : 50000*4     =    200,000   } zeroed each call
    //   counts @ 38,600,000 : 1024*4      =      4,096   } (single memset,
    //   xc     @ 38,604,096 : 1024*128*4  =    524,288   }  728,384 bytes)
    //   assign @ 39,128,384 : 50000*4     =    200,000
    //   y      @ 39,328,384 : 1024*128*4  =    524,288
    float* h      = (float*)(ws);
    int*   bucket = (int*)(ws + 25600000);
    int*   cursor = (int*)(ws + 38400000);
    int*   counts = (int*)(ws + 38600000);
    float* xc     = (float*)(ws + 38604096);
    int*   assign = (int*)(ws + 39128384);
    float* y      = (float*)(ws + 39328384);
    float* hn     = out;  // hn lives in d_out; fully overwritten by scatter_out_k

    hipMemsetAsync(ws + 38400000, 0, 728384, stream);

    fill_buckets_k<<<(N_EDGES + 255) / 256, 256, 0, stream>>>(ei, bucket, cursor);
    agg_norm_k<<<N_NODES / 4, 256, 0, stream>>>(x, bucket, cursor, h, hn);
    sim_argmax_k<<<(N_NODES + 63) / 64, 64, 0, stream>>>(hn, assign);
    cluster_acc_k<<<(N_NODES * 32) / 256, 256, 0, stream>>>(h, assign, xc, counts);
    y_gemm_k<<<KC, 128, 0, stream>>>(xc, counts, W1, b1, y);
    scatter_out_k<<<(N_NODES * 32) / 256, 256, 0, stream>>>(y, assign, out);
}

// Round 2
// 379.838 us; speedup vs baseline: 2.9202x; 2.9202x over previous
//
#include <hip/hip_runtime.h>

#define N_NODES 50000
#define N_EDGES 500000
#define DIM 128
#define KC 1024
#define CAP 64
#define EPSV 1e-8f
#define TM 64
#define TN 128
#define KS 16

// map float to order-preserving uint (for packed atomicMax argmax)
__device__ __forceinline__ unsigned ford(float f) {
    unsigned b = __float_as_uint(f);
    return (b & 0x80000000u) ? ~b : (b | 0x80000000u);
}

// ---------------- Stage 1a: bucket edges by dst (int atomics only) ----------------
__global__ void fill_buckets_k(const int* __restrict__ ei, int* __restrict__ bucket,
                               int* __restrict__ cursor) {
    int e = blockIdx.x * blockDim.x + threadIdx.x;
    if (e >= N_EDGES) return;
    int src = ei[e];
    int dst = ei[N_EDGES + e];
    int pos = atomicAdd(cursor + dst, 1);
    if (pos < CAP) bucket[dst * CAP + pos] = src;
}

// ---------------- Stage 1b+2: deterministic mean-aggregate + L2 normalize ----------
__global__ void agg_norm_k(const float* __restrict__ x, const int* __restrict__ bucket,
                           const int* __restrict__ cursor, float* __restrict__ h,
                           float* __restrict__ hn) {
    int lane = threadIdx.x & 63;
    int wv = threadIdx.x >> 6;
    int n = blockIdx.x * 4 + wv;  // grid 12500 * 4 waves = 50000 exactly

    int cnt = cursor[n];
    if (cnt > CAP) cnt = CAP;
    int v = (lane < cnt) ? bucket[n * CAP + lane] : 0x7fffffff;

    // bitonic sort ascending across 64 lanes -> deterministic sum order
#pragma unroll
    for (int k = 2; k <= 64; k <<= 1) {
#pragma unroll
        for (int j = k >> 1; j >= 1; j >>= 1) {
            int other = __shfl_xor(v, j);
            bool lower = ((lane & j) == 0);
            bool asc = ((lane & k) == 0);
            int mn = min(v, other), mx = max(v, other);
            v = (lower == asc) ? mn : mx;
        }
    }

    const float2* x2 = (const float2*)x;
    float ax = 0.f, ay = 0.f;
    for (int j = 0; j < cnt; ++j) {
        int s = __shfl(v, j);
        float2 t = x2[(size_t)s * 64 + lane];
        ax += t.x; ay += t.y;
    }
    float degf = (float)(cnt > 0 ? cnt : 1);
    float hx = ax / degf, hy = ay / degf;

    float ss = hx * hx + hy * hy;
#pragma unroll
    for (int o = 1; o < 64; o <<= 1) ss += __shfl_xor(ss, o);
    float denom = sqrtf(ss) + EPSV;

    ((float2*)h)[(size_t)n * 64 + lane] = make_float2(hx, hy);
    ((float2*)hn)[(size_t)n * 64 + lane] = make_float2(hx / denom, hy / denom);
}

// ---------------- Stage 3: tiled vector GEMM + fused argmax ----------------
// block 256 thr: 64 nodes x 128 cents, per-thread 4x8 micro-tile, K chunks of 16.
// argmax combined across N-blocks via packed u64 atomicMax (order-independent).
__global__ __launch_bounds__(256, 4) void sim_argmax2_k(const float* __restrict__ hn,
                                                        unsigned long long* __restrict__ keys) {
    __shared__ float Asb[KS][TM];   // k-major
    __shared__ float Bsb[KS][TN];   // k-major
    const int tid = threadIdx.x;
    const int tx = tid & 15, ty = tid >> 4;
    const int m0 = blockIdx.x * TM;
    const int n0 = blockIdx.y * TN;

    float acc[4][8];
#pragma unroll
    for (int i = 0; i < 4; ++i)
#pragma unroll
        for (int j = 0; j < 8; ++j) acc[i][j] = 0.f;

    // staging assignments
    const int an = tid >> 2;             // node 0..63
    const int ak = (tid & 3) << 2;       // k offset 0,4,8,12
    int agn = m0 + an; if (agn >= N_NODES) agn = N_NODES - 1;  // clamp tail (dup, write skipped)
    const float* aptr = hn + (size_t)agn * DIM + ak;
    const int bc = tid >> 1;             // cent 0..127
    const int bk = (tid & 1) << 3;       // k offset 0,8
    const float* bptr = hn + (size_t)(n0 + bc) * DIM + bk;

    for (int kc = 0; kc < DIM; kc += KS) {
        float4 av = *(const float4*)(aptr + kc);
        float4 b0 = *(const float4*)(bptr + kc);
        float4 b1 = *(const float4*)(bptr + kc + 4);
        Asb[ak + 0][an] = av.x; Asb[ak + 1][an] = av.y;
        Asb[ak + 2][an] = av.z; Asb[ak + 3][an] = av.w;
        Bsb[bk + 0][bc] = b0.x; Bsb[bk + 1][bc] = b0.y;
        Bsb[bk + 2][bc] = b0.z; Bsb[bk + 3][bc] = b0.w;
        Bsb[bk + 4][bc] = b1.x; Bsb[bk + 5][bc] = b1.y;
        Bsb[bk + 6][bc] = b1.z; Bsb[bk + 7][bc] = b1.w;
        __syncthreads();
#pragma unroll
        for (int kk = 0; kk < KS; ++kk) {
            float a_[4], b_[8];
            float4 a = *(const float4*)&Asb[kk][ty << 2];
            float4 p = *(const float4*)&Bsb[kk][tx << 3];
            float4 q = *(const float4*)&Bsb[kk][(tx << 3) + 4];
            a_[0] = a.x; a_[1] = a.y; a_[2] = a.z; a_[3] = a.w;
            b_[0] = p.x; b_[1] = p.y; b_[2] = p.z; b_[3] = p.w;
            b_[4] = q.x; b_[5] = q.y; b_[6] = q.z; b_[7] = q.w;
#pragma unroll
            for (int i = 0; i < 4; ++i)
#pragma unroll
                for (int j = 0; j < 8; ++j)
                    acc[i][j] = fmaf(a_[i], b_[j], acc[i][j]);
        }
        __syncthreads();
    }

    // fused argmax: per node-row, scan 8 local cents (ascending -> first-max), then
    // shfl-reduce across the 16 tx lanes, then atomicMax across the 8 N-blocks.
#pragma unroll
    for (int i = 0; i < 4; ++i) {
        float best = acc[i][0];
        int bj = 0;
#pragma unroll
        for (int j = 1; j < 8; ++j)
            if (acc[i][j] > best) { best = acc[i][j]; bj = j; }
        int bidx = n0 + (tx << 3) + bj;
#pragma unroll
        for (int o = 1; o < 16; o <<= 1) {
            float os = __shfl_xor(best, o);
            int oi = __shfl_xor(bidx, o);
            if (os > best || (os == best && oi < bidx)) { best = os; bidx = oi; }
        }
        if (tx == 0) {
            int gn = m0 + (ty << 2) + i;
            if (gn < N_NODES) {
                unsigned long long key =
                    ((unsigned long long)ford(best) << 32) | (unsigned)(KC - 1 - bidx);
                atomicMax(keys + gn, key);
            }
        }
    }
}

// ---------------- Stage 3b: decode packed keys -> assign ----------------
__global__ void decode_k(const unsigned long long* __restrict__ keys,
                         int* __restrict__ assign) {
    int n = blockIdx.x * 256 + threadIdx.x;
    if (n >= N_NODES) return;
    assign[n] = (KC - 1) - (int)(unsigned)(keys[n] & 0xFFFFFFFFull);
}

// ---------------- Stage 4: cluster sums (float atomics OK: smooth path) ----------
__global__ void cluster_acc_k(const float* __restrict__ h, const int* __restrict__ assign,
                              float* __restrict__ xc, int* __restrict__ counts) {
    int i = blockIdx.x * blockDim.x + threadIdx.x;  // 50000*32 exactly
    int n = i >> 5, q = i & 31;
    int a = assign[n];
    float4 v = ((const float4*)h)[(size_t)n * 32 + q];
    float* d = xc + a * DIM + q * 4;
    atomicAdd(d + 0, v.x);
    atomicAdd(d + 1, v.y);
    atomicAdd(d + 2, v.z);
    atomicAdd(d + 3, v.w);
    if (q == 0) atomicAdd(counts + a, 1);
}

// ---------------- Stage 5: y = (xc/counts) @ W1.T + b1 ----------------
__global__ void y_gemm_k(const float* __restrict__ xc, const int* __restrict__ counts,
                         const float* __restrict__ W1, const float* __restrict__ b1,
                         float* __restrict__ y) {
    __shared__ float xr[DIM];
    int c = blockIdx.x, t = threadIdx.x;  // 1024 blocks x 128 threads
    int cnt = counts[c];
    float cntf = (float)(cnt > 0 ? cnt : 1);
    xr[t] = xc[c * DIM + t] / cntf;
    __syncthreads();

    const float4* w4 = (const float4*)(W1 + t * DIM);
    float a0 = 0.f, a1 = 0.f, a2 = 0.f, a3 = 0.f;
#pragma unroll
    for (int kk = 0; kk < 32; ++kk) {
        float4 w = w4[kk];
        a0 = fmaf(xr[4 * kk + 0], w.x, a0);
        a1 = fmaf(xr[4 * kk + 1], w.y, a1);
        a2 = fmaf(xr[4 * kk + 2], w.z, a2);
        a3 = fmaf(xr[4 * kk + 3], w.w, a3);
    }
    y[c * DIM + t] = (a0 + a1) + (a2 + a3) + b1[t];
}

// ---------------- Stage 6: out = y[assign] ----------------
__global__ void scatter_out_k(const float* __restrict__ y, const int* __restrict__ assign,
                              float* __restrict__ out) {
    int i = blockIdx.x * blockDim.x + threadIdx.x;  // 50000*32 exactly
    int n = i >> 5, q = i & 31;
    int a = assign[n];
    ((float4*)out)[(size_t)n * 32 + q] = ((const float4*)y)[a * 32 + q];
}

extern "C" void kernel_launch(void* const* d_in, const int* in_sizes, int n_in,
                              void* d_out, int out_size, void* d_ws, size_t ws_size,
                              hipStream_t stream) {
    const float* x  = (const float*)d_in[0];
    const int*   ei = (const int*)d_in[1];
    const float* W1 = (const float*)d_in[2];
    const float* b1 = (const float*)d_in[3];
    float* out = (float*)d_out;

    char* ws = (char*)d_ws;
    // layout (bytes):
    //   h      @ 0          : 50000*128*4 = 25,600,000
    //   bucket @ 25,600,000 : 50000*64*4  = 12,800,000   (keys reuses this after agg)
    //   cursor @ 38,400,000 : 50000*4     =    200,000
    //   counts @ 38,600,000 : 1024*4      =      4,096
    //   xc     @ 38,604,096 : 1024*128*4  =    524,288
    //   assign @ 39,128,384 : 50000*4     =    200,000
    //   y      @ 39,328,384 : 1024*128*4  =    524,288
    float* h      = (float*)(ws);
    int*   bucket = (int*)(ws + 25600000);
    int*   cursor = (int*)(ws + 38400000);
    int*   counts = (int*)(ws + 38600000);
    float* xc     = (float*)(ws + 38604096);
    int*   assign = (int*)(ws + 39128384);
    float* y      = (float*)(ws + 39328384);
    float* hn     = out;  // hn lives in d_out; fully overwritten by scatter_out_k
    unsigned long long* keys = (unsigned long long*)(ws + 25600000);  // reuse bucket

    hipMemsetAsync(ws + 38400000, 0, 728384, stream);  // cursor + counts + xc

    fill_buckets_k<<<(N_EDGES + 255) / 256, 256, 0, stream>>>(ei, bucket, cursor);
    agg_norm_k<<<N_NODES / 4, 256, 0, stream>>>(x, bucket, cursor, h, hn);
    hipMemsetAsync(ws + 25600000, 0, N_NODES * 8, stream);  // zero keys (bucket is dead)
    sim_argmax2_k<<<dim3((N_NODES + TM - 1) / TM, KC / TN), 256, 0, stream>>>(hn, keys);
    decode_k<<<(N_NODES + 255) / 256, 256, 0, stream>>>(keys, assign);
    cluster_acc_k<<<(N_NODES * 32) / 256, 256, 0, stream>>>(h, assign, xc, counts);
    y_gemm_k<<<KC, 128, 0, stream>>>(xc, counts, W1, b1, y);
    scatter_out_k<<<(N_NODES * 32) / 256, 256, 0, stream>>>(y, assign, out);
}

// Round 3
// 363.832 us; speedup vs baseline: 3.0486x; 1.0440x over previous
//
#include <hip/hip_runtime.h>

#define N_NODES 50000
#define N_EDGES 500000
#define DIM 128
#define KC 1024
#define CAP 64
#define EPSV 1e-8f
#define TM 128
#define TN 128
#define KS 16

// map float to order-preserving uint (for packed atomicMax argmax)
__device__ __forceinline__ unsigned ford(float f) {
    unsigned b = __float_as_uint(f);
    return (b & 0x80000000u) ? ~b : (b | 0x80000000u);
}

// ---------------- Stage 1a: bucket edges by dst (int atomics only) ----------------
__global__ void fill_buckets_k(const int* __restrict__ ei, int* __restrict__ bucket,
                               int* __restrict__ cursor) {
    int e = blockIdx.x * blockDim.x + threadIdx.x;
    if (e >= N_EDGES) return;
    int src = ei[e];
    int dst = ei[N_EDGES + e];
    int pos = atomicAdd(cursor + dst, 1);
    if (pos < CAP) bucket[dst * CAP + pos] = src;
}

// ---------------- Stage 1b+2: deterministic mean-aggregate + L2 normalize ----------
__global__ void agg_norm_k(const float* __restrict__ x, const int* __restrict__ bucket,
                           const int* __restrict__ cursor, float* __restrict__ h,
                           float* __restrict__ hn) {
    int lane = threadIdx.x & 63;
    int wv = threadIdx.x >> 6;
    int n = blockIdx.x * 4 + wv;  // grid 12500 * 4 waves = 50000 exactly

    int cnt = cursor[n];
    if (cnt > CAP) cnt = CAP;
    int v = (lane < cnt) ? bucket[n * CAP + lane] : 0x7fffffff;

    // bitonic sort ascending across 64 lanes -> deterministic sum order
#pragma unroll
    for (int k = 2; k <= 64; k <<= 1) {
#pragma unroll
        for (int j = k >> 1; j >= 1; j >>= 1) {
            int other = __shfl_xor(v, j);
            bool lower = ((lane & j) == 0);
            bool asc = ((lane & k) == 0);
            int mn = min(v, other), mx = max(v, other);
            v = (lower == asc) ? mn : mx;
        }
    }

    const float2* x2 = (const float2*)x;
    float ax = 0.f, ay = 0.f;
    for (int j = 0; j < cnt; ++j) {
        int s = __shfl(v, j);
        float2 t = x2[(size_t)s * 64 + lane];
        ax += t.x; ay += t.y;
    }
    float degf = (float)(cnt > 0 ? cnt : 1);
    float hx = ax / degf, hy = ay / degf;

    float ss = hx * hx + hy * hy;
#pragma unroll
    for (int o = 1; o < 64; o <<= 1) ss += __shfl_xor(ss, o);
    float denom = sqrtf(ss) + EPSV;

    ((float2*)h)[(size_t)n * 64 + lane] = make_float2(hx, hy);
    ((float2*)hn)[(size_t)n * 64 + lane] = make_float2(hx / denom, hy / denom);
}

// ---------------- Stage 3: tiled vector GEMM + fused argmax ----------------
// 128x128 tile, 256 threads, per-thread 8x8 in split quadrants:
// rows {ty*4+i, 64+ty*4+i}, cols {tx*4+j, 64+tx*4+j} -> all fragment reads are
// 16B-stride over 16 lanes = exact 2x bank wrap = conflict-free. 64 FMA / 4 ds_read.
__global__ __launch_bounds__(256, 4) void sim_argmax3_k(const float* __restrict__ hn,
                                                        unsigned long long* __restrict__ keys) {
    __shared__ float Asb[KS][TM];   // k-major
    __shared__ float Bsb[KS][TN];   // k-major
    const int tid = threadIdx.x;
    const int tx = tid & 15, ty = tid >> 4;
    const int m0 = blockIdx.x * TM;
    const int n0 = blockIdx.y * TN;

    float acc[8][8];
#pragma unroll
    for (int i = 0; i < 8; ++i)
#pragma unroll
        for (int j = 0; j < 8; ++j) acc[i][j] = 0.f;

    // staging: 2 threads per row, 8 floats each (k-major scatter, 2-way = free)
    const int an = tid >> 1;             // 0..127
    const int ak = (tid & 1) << 3;       // 0 or 8
    int agn = m0 + an; if (agn >= N_NODES) agn = N_NODES - 1;  // clamp tail (dup)
    const float* aptr = hn + (size_t)agn * DIM + ak;
    const float* bptr = hn + (size_t)(n0 + an) * DIM + ak;

    for (int kc = 0; kc < DIM; kc += KS) {
        float4 a0 = *(const float4*)(aptr + kc);
        float4 a1 = *(const float4*)(aptr + kc + 4);
        float4 b0 = *(const float4*)(bptr + kc);
        float4 b1 = *(const float4*)(bptr + kc + 4);
        Asb[ak + 0][an] = a0.x; Asb[ak + 1][an] = a0.y;
        Asb[ak + 2][an] = a0.z; Asb[ak + 3][an] = a0.w;
        Asb[ak + 4][an] = a1.x; Asb[ak + 5][an] = a1.y;
        Asb[ak + 6][an] = a1.z; Asb[ak + 7][an] = a1.w;
        Bsb[ak + 0][an] = b0.x; Bsb[ak + 1][an] = b0.y;
        Bsb[ak + 2][an] = b0.z; Bsb[ak + 3][an] = b0.w;
        Bsb[ak + 4][an] = b1.x; Bsb[ak + 5][an] = b1.y;
        Bsb[ak + 6][an] = b1.z; Bsb[ak + 7][an] = b1.w;
        __syncthreads();
#pragma unroll
        for (int kk = 0; kk < KS; ++kk) {
            float4 ar0 = *(const float4*)&Asb[kk][ty << 2];
            float4 ar1 = *(const float4*)&Asb[kk][64 + (ty << 2)];
            float4 br0 = *(const float4*)&Bsb[kk][tx << 2];
            float4 br1 = *(const float4*)&Bsb[kk][64 + (tx << 2)];
            float a_[8] = {ar0.x, ar0.y, ar0.z, ar0.w, ar1.x, ar1.y, ar1.z, ar1.w};
            float b_[8] = {br0.x, br0.y, br0.z, br0.w, br1.x, br1.y, br1.z, br1.w};
#pragma unroll
            for (int i = 0; i < 8; ++i)
#pragma unroll
                for (int j = 0; j < 8; ++j)
                    acc[i][j] = fmaf(a_[i], b_[j], acc[i][j]);
        }
        __syncthreads();
    }

    // fused argmax. per-thread col of acc j: global cent = n0 + (j<4 ? tx*4+j : 64+tx*4+j-4)
    // -> ascending in j for every thread, so strict > keeps the first max.
#pragma unroll
    for (int i = 0; i < 8; ++i) {
        float best = acc[i][0];
        int bj = 0;
#pragma unroll
        for (int j = 1; j < 8; ++j)
            if (acc[i][j] > best) { best = acc[i][j]; bj = j; }
        int bidx = n0 + ((bj < 4) ? ((tx << 2) + bj) : (64 + (tx << 2) + bj - 4));
#pragma unroll
        for (int o = 1; o < 16; o <<= 1) {
            float os = __shfl_xor(best, o);
            int oi = __shfl_xor(bidx, o);
            if (os > best || (os == best && oi < bidx)) { best = os; bidx = oi; }
        }
        if (tx == 0) {
            int gn = m0 + ((i < 4) ? ((ty << 2) + i) : (64 + (ty << 2) + i - 4));
            if (gn < N_NODES) {
                unsigned long long key =
                    ((unsigned long long)ford(best) << 32) | (unsigned)(KC - 1 - bidx);
                atomicMax(keys + gn, key);
            }
        }
    }
}

// ---------------- Stage 3b: decode packed keys -> assign ----------------
__global__ void decode_k(const unsigned long long* __restrict__ keys,
                         int* __restrict__ assign) {
    int n = blockIdx.x * 256 + threadIdx.x;
    if (n >= N_NODES) return;
    assign[n] = (KC - 1) - (int)(unsigned)(keys[n] & 0xFFFFFFFFull);
}

// ---------------- Stage 4: cluster sums (float atomics OK: smooth path) ----------
__global__ void cluster_acc_k(const float* __restrict__ h, const int* __restrict__ assign,
                              float* __restrict__ xc, int* __restrict__ counts) {
    int i = blockIdx.x * blockDim.x + threadIdx.x;  // 50000*32 exactly
    int n = i >> 5, q = i & 31;
    int a = assign[n];
    float4 v = ((const float4*)h)[(size_t)n * 32 + q];
    float* d = xc + a * DIM + q * 4;
    atomicAdd(d + 0, v.x);
    atomicAdd(d + 1, v.y);
    atomicAdd(d + 2, v.z);
    atomicAdd(d + 3, v.w);
    if (q == 0) atomicAdd(counts + a, 1);
}

// ---------------- Stage 5: y = (xc/counts) @ W1.T + b1 ----------------
__global__ void y_gemm_k(const float* __restrict__ xc, const int* __restrict__ counts,
                         const float* __restrict__ W1, const float* __restrict__ b1,
                         float* __restrict__ y) {
    __shared__ float xr[DIM];
    int c = blockIdx.x, t = threadIdx.x;  // 1024 blocks x 128 threads
    int cnt = counts[c];
    float cntf = (float)(cnt > 0 ? cnt : 1);
    xr[t] = xc[c * DIM + t] / cntf;
    __syncthreads();

    const float4* w4 = (const float4*)(W1 + t * DIM);
    float a0 = 0.f, a1 = 0.f, a2 = 0.f, a3 = 0.f;
#pragma unroll
    for (int kk = 0; kk < 32; ++kk) {
        float4 w = w4[kk];
        a0 = fmaf(xr[4 * kk + 0], w.x, a0);
        a1 = fmaf(xr[4 * kk + 1], w.y, a1);
        a2 = fmaf(xr[4 * kk + 2], w.z, a2);
        a3 = fmaf(xr[4 * kk + 3], w.w, a3);
    }
    y[c * DIM + t] = (a0 + a1) + (a2 + a3) + b1[t];
}

// ---------------- Stage 6: out = y[assign] ----------------
__global__ void scatter_out_k(const float* __restrict__ y, const int* __restrict__ assign,
                              float* __restrict__ out) {
    int i = blockIdx.x * blockDim.x + threadIdx.x;  // 50000*32 exactly
    int n = i >> 5, q = i & 31;
    int a = assign[n];
    ((float4*)out)[(size_t)n * 32 + q] = ((const float4*)y)[a * 32 + q];
}

extern "C" void kernel_launch(void* const* d_in, const int* in_sizes, int n_in,
                              void* d_out, int out_size, void* d_ws, size_t ws_size,
                              hipStream_t stream) {
    const float* x  = (const float*)d_in[0];
    const int*   ei = (const int*)d_in[1];
    const float* W1 = (const float*)d_in[2];
    const float* b1 = (const float*)d_in[3];
    float* out = (float*)d_out;

    char* ws = (char*)d_ws;
    // layout (bytes):
    //   h      @ 0          : 50000*128*4 = 25,600,000
    //   bucket @ 25,600,000 : 50000*64*4  = 12,800,000   (keys reuses this after agg)
    //   cursor @ 38,400,000 : 50000*4     =    200,000
    //   counts @ 38,600,000 : 1024*4      =      4,096
    //   xc     @ 38,604,096 : 1024*128*4  =    524,288
    //   assign @ 39,128,384 : 50000*4     =    200,000
    //   y      @ 39,328,384 : 1024*128*4  =    524,288
    float* h      = (float*)(ws);
    int*   bucket = (int*)(ws + 25600000);
    int*   cursor = (int*)(ws + 38400000);
    int*   counts = (int*)(ws + 38600000);
    float* xc     = (float*)(ws + 38604096);
    int*   assign = (int*)(ws + 39128384);
    float* y      = (float*)(ws + 39328384);
    float* hn     = out;  // hn lives in d_out; fully overwritten by scatter_out_k
    unsigned long long* keys = (unsigned long long*)(ws + 25600000);  // reuse bucket

    hipMemsetAsync(ws + 38400000, 0, 728384, stream);  // cursor + counts + xc

    fill_buckets_k<<<(N_EDGES + 255) / 256, 256, 0, stream>>>(ei, bucket, cursor);
    agg_norm_k<<<N_NODES / 4, 256, 0, stream>>>(x, bucket, cursor, h, hn);
    hipMemsetAsync(ws + 25600000, 0, N_NODES * 8, stream);  // zero keys (bucket is dead)
    sim_argmax3_k<<<dim3((N_NODES + TM - 1) / TM, KC / TN), 256, 0, stream>>>(hn, keys);
    decode_k<<<(N_NODES + 255) / 256, 256, 0, stream>>>(keys, assign);
    cluster_acc_k<<<(N_NODES * 32) / 256, 256, 0, stream>>>(h, assign, xc, counts);
    y_gemm_k<<<KC, 128, 0, stream>>>(xc, counts, W1, b1, y);
    scatter_out_k<<<(N_NODES * 32) / 256, 256, 0, stream>>>(y, assign, out);
}